// Round 8
// baseline (143.922 us; speedup 1.0000x reference)
//
#include <hip/hip_runtime.h>
#include <math.h>

// Problem constants (fixed by the reference)
#define NB   256                 // graphs
#define NPG  256                 // nodes per graph
#define NN   (NB * NPG)          // 65536 nodes
#define NE   (NN * 16)           // 1048576 edges
#define EPG  (NE / NB)           // 4096 edges per graph
#define FD   128                 // F == H
#define NC   10
#define NSL  32                  // slices (1024 threads / 32 lanes-per-slice)
#define NEG_INF (-3.402823466e38f)

// Shared-memory layout for the fused per-graph block: 162,896 B <= 160 KiB.
struct SM {
    float hs[NPG][FD];          // 128 KB: x -> dinv-scaled hW -> gated h (in place)
    int   rp[NPG + 4];          // local CSR row pointers
    float nml[NPG];             // node mask
    float dvv[NPG];             // dinv
    float sw[NPG];              // score matvec result / MLP h1
    float sf[NPG];              // score conv result (by node id) / MLP h2
    float svv[NPG];             // sort value staging / MLP logits
    float th[NPG];              // tanh(score) for kept
    float zacc[2 * FD];         // readout accumulator across levels
    int   si[NPG];              // CSR counts / sort index staging
    int   kept[NPG];            // kept flags / CSR scatter cursor
    int   anode[NPG];           // active list
    int   wsum[16];             // wave-scan partials
    float red_mx[16][FD];       // per-wave readout partials
    float red_sm[16][FD];
    unsigned char colb[EPG];    // edge src local ids (CSR-by-dst order), 4 KB
};

// Swizzled access to feature-quad q (16B) of row v: physical quad = q ^ (v&7).
__device__ __forceinline__ float4& hsq(SM& sm, int v, int q) {
    return *(float4*)&sm.hs[v][(q ^ (v & 7)) << 2];
}

// ---------------------------------------------------------------------------
// One pooling level, fully in-LDS. NACT = active node count (256/128/64).
// Thread layout: f4 = tid&31 (feature quad), s = tid>>5 (slice 0..31);
// slice s owns active indices i = c*32+s, c < NPS = NACT/32.
// hs rows of ACTIVE nodes hold dinv-scaled h after GEMM; inactive rows are 0.
// ---------------------------------------------------------------------------
template <int NACT, bool FIRST>
__device__ __forceinline__ void do_level(SM& sm,
                                         const float* __restrict__ Wmat,
                                         const float* __restrict__ bias,
                                         const float* __restrict__ Wp,
                                         const float* __restrict__ bpp,
                                         int tid) {
    constexpr int NPS = NACT / NSL;      // rows per slice
    constexpr int K   = NACT / 2;
    constexpr int TPN = 1024 / NACT;     // threads per node in score conv
    const int f4 = tid & 31;
    const int s  = tid >> 5;

    // ---- dinv: 4 threads per node (level-1 dvv precomputed from degrees) ----
    if (!FIRST) {
        const int n = tid >> 2, sub = tid & 3;
        float part = 0.f;
        const float nmn = sm.nml[n];
        if (nmn > 0.f) {
            const int e1 = sm.rp[n + 1];
            for (int e = sm.rp[n] + sub; e < e1; e += 4)
                part += sm.nml[sm.colb[e]];
        }
        part += __shfl_xor(part, 1);
        part += __shfl_xor(part, 2);
        if (sub == 0) sm.dvv[n] = (nmn > 0.f) ? rsqrtf(1.f + part) : 0.f;
        __syncthreads();   // GEMM epilogue reads dvv
    }

    // ---- in-place GEMM + dinv prescale: hs[v] <- dvv[v] * (hs[v] @ W) ----
    // Row v is read and written only by the 32 lanes of the half-wave that
    // owns it (lockstep) -> no barrier needed around the in-place update.
    {
        int vr[NPS];
        float4 acc[NPS];
#pragma unroll
        for (int c = 0; c < NPS; ++c) {
            vr[c] = sm.anode[c * NSL + s];
            acc[c] = make_float4(0.f, 0.f, 0.f, 0.f);
        }
#pragma unroll 2
        for (int kq = 0; kq < 32; ++kq) {
            const int k0 = kq << 2;
            float4 w0 = *(const float4*)&Wmat[(k0 + 0) * FD + 4 * f4];
            float4 w1 = *(const float4*)&Wmat[(k0 + 1) * FD + 4 * f4];
            float4 w2 = *(const float4*)&Wmat[(k0 + 2) * FD + 4 * f4];
            float4 w3 = *(const float4*)&Wmat[(k0 + 3) * FD + 4 * f4];
#pragma unroll
            for (int c = 0; c < NPS; ++c) {
                float4 hv = hsq(sm, vr[c], kq);
                acc[c].x += hv.x * w0.x + hv.y * w1.x + hv.z * w2.x + hv.w * w3.x;
                acc[c].y += hv.x * w0.y + hv.y * w1.y + hv.z * w2.y + hv.w * w3.y;
                acc[c].z += hv.x * w0.z + hv.y * w1.z + hv.z * w2.z + hv.w * w3.z;
                acc[c].w += hv.x * w0.w + hv.y * w1.w + hv.z * w2.w + hv.w * w3.w;
            }
        }
#pragma unroll
        for (int c = 0; c < NPS; ++c) {
            const float d = sm.dvv[vr[c]];
            acc[c].x *= d; acc[c].y *= d; acc[c].z *= d; acc[c].w *= d;
            hsq(sm, vr[c], f4) = acc[c];
        }
    }
    __syncthreads();   // publishes scaled GEMM rows

    // ---- conv + relu + fused score matvec (pure-add gather) ----
    const float4 b4  = *(const float4*)&bias[4 * f4];
    const float4 wp4 = *(const float4*)&Wp[4 * f4];
    float4 hreg[NPS];
#pragma unroll
    for (int c = 0; c < NPS; ++c) {
        const int v = sm.anode[c * NSL + s];
        const float dv_ = sm.dvv[v];
        float4 S = hsq(sm, v, f4);                 // scaled self term
        const int e0 = sm.rp[v], e1 = sm.rp[v + 1];
        int e = e0;
        int ea = (e0 + 3) & ~3;                     // align head
        if (ea > e1) ea = e1;
        for (; e < ea; ++e) {
            float4 hu = hsq(sm, sm.colb[e], f4);
            S.x += hu.x; S.y += hu.y; S.z += hu.z; S.w += hu.w;
        }
        for (; e + 4 <= e1; e += 4) {
            unsigned p = *(const unsigned*)&sm.colb[e];
            int u0 = p & 255, u1 = (p >> 8) & 255;
            int u2 = (p >> 16) & 255, u3 = p >> 24;
            float4 h0 = hsq(sm, u0, f4);
            float4 h1 = hsq(sm, u1, f4);
            float4 h2 = hsq(sm, u2, f4);
            float4 h3 = hsq(sm, u3, f4);
            S.x += h0.x + h1.x + h2.x + h3.x;
            S.y += h0.y + h1.y + h2.y + h3.y;
            S.z += h0.z + h1.z + h2.z + h3.z;
            S.w += h0.w + h1.w + h2.w + h3.w;
        }
        for (; e < e1; ++e) {
            float4 hu = hsq(sm, sm.colb[e], f4);
            S.x += hu.x; S.y += hu.y; S.z += hu.z; S.w += hu.w;
        }
        float4 acc;
        acc.x = fmaxf(S.x * dv_ + b4.x, 0.f);
        acc.y = fmaxf(S.y * dv_ + b4.y, 0.f);
        acc.z = fmaxf(S.z * dv_ + b4.z, 0.f);
        acc.w = fmaxf(S.w * dv_ + b4.w, 0.f);
        hreg[c] = acc;
        // score partial: dot(h[v], Wp) reduced across the 32 f4 lanes
        float p = acc.x * wp4.x + acc.y * wp4.y + acc.z * wp4.z + acc.w * wp4.w;
        p += __shfl_xor(p, 1);
        p += __shfl_xor(p, 2);
        p += __shfl_xor(p, 4);
        p += __shfl_xor(p, 8);
        p += __shfl_xor(p, 16);
        if (f4 == 0) sm.sw[v] = p;
    }
    __syncthreads();

    // ---- score conv: TPN threads per active node ----
    {
        const int i = tid / TPN, sub = tid % TPN;
        const int v = sm.anode[i];
        const float dv_ = sm.dvv[v];
        float part = 0.f;
        const int e1 = sm.rp[v + 1];
        for (int e = sm.rp[v] + sub; e < e1; e += TPN) {
            int u = sm.colb[e];
            part += sm.dvv[u] * sm.sw[u];
        }
#pragma unroll
        for (int o = 1; o < TPN; o <<= 1) part += __shfl_xor(part, o);
        if (sub == 0) {
            float acc = sm.sw[v] * dv_ * dv_ + bpp[0] + dv_ * part;
            sm.sf[v] = acc;        // by node id (for tanh later)
            sm.svv[i] = acc;       // by active index (for sort)
        }
    }
    __syncthreads();

    // ---- bitonic sort of NACT active elements, registers + shuffles ----
    // comparator: value desc, node-id asc  (= jax.lax.top_k semantics)
    float v_ = 0.f;
    int   id_ = 0;
    if (tid < NACT) { v_ = sm.svv[tid]; id_ = sm.anode[tid]; }
#pragma unroll
    for (int k = 2; k <= NACT; k <<= 1) {
#pragma unroll
        for (int j = k >> 1; j > 0; j >>= 1) {
            if (j < 64) {
                if (tid < NACT) {
                    float vp = __shfl_xor(v_, j);
                    int  idp = __shfl_xor(id_, j);
                    bool up    = ((tid & k) == 0);
                    bool lower = ((tid & j) == 0);
                    bool g = (v_ > vp) || (v_ == vp && id_ < idp);
                    if (g != (lower == up)) { v_ = vp; id_ = idp; }
                }
            } else {
                if (tid < NACT) { sm.svv[tid] = v_; sm.si[tid] = id_; }
                __syncthreads();
                if (tid < NACT) {
                    int p = tid ^ j;
                    float vp = sm.svv[p];
                    int  idp = sm.si[p];
                    bool up    = ((tid & k) == 0);
                    bool lower = ((tid & j) == 0);
                    bool g = (v_ > vp) || (v_ == vp && id_ < idp);
                    if (g != (lower == up)) { v_ = vp; id_ = idp; }
                }
                __syncthreads();
            }
        }
    }
    if (tid < NPG) sm.kept[tid] = 0;
    __syncthreads();
    if (tid < K) {
        sm.kept[id_] = 1;
        sm.th[id_] = tanhf(sm.sf[id_]);
    }
    __syncthreads();

    // ---- tanh-gate: write kept rows (0 for non-kept!); readout partials ----
    float4 mx4 = make_float4(NEG_INF, NEG_INF, NEG_INF, NEG_INF);
    float4 sm4 = make_float4(0.f, 0.f, 0.f, 0.f);
#pragma unroll
    for (int c = 0; c < NPS; ++c) {
        const int v = sm.anode[c * NSL + s];
        const int kp = sm.kept[v];
        const float tg = kp ? sm.th[v] : 0.f;
        float4 val;
        val.x = hreg[c].x * tg;
        val.y = hreg[c].y * tg;
        val.z = hreg[c].z * tg;
        val.w = hreg[c].w * tg;
        hsq(sm, v, f4) = val;                 // zeros dropped rows
        if (kp) {
            mx4.x = fmaxf(mx4.x, val.x);
            mx4.y = fmaxf(mx4.y, val.y);
            mx4.z = fmaxf(mx4.z, val.z);
            mx4.w = fmaxf(mx4.w, val.w);
        }
        sm4.x += val.x; sm4.y += val.y; sm4.z += val.z; sm4.w += val.w;
    }
    mx4.x = fmaxf(mx4.x, __shfl_xor(mx4.x, 32)); sm4.x += __shfl_xor(sm4.x, 32);
    mx4.y = fmaxf(mx4.y, __shfl_xor(mx4.y, 32)); sm4.y += __shfl_xor(sm4.y, 32);
    mx4.z = fmaxf(mx4.z, __shfl_xor(mx4.z, 32)); sm4.z += __shfl_xor(sm4.z, 32);
    mx4.w = fmaxf(mx4.w, __shfl_xor(mx4.w, 32)); sm4.w += __shfl_xor(sm4.w, 32);
    const int wv = tid >> 6;
    if ((tid & 63) < 32) {
        *(float4*)&sm.red_mx[wv][4 * f4] = mx4;
        *(float4*)&sm.red_sm[wv][4 * f4] = sm4;
    }
    __syncthreads();
    if (tid < FD) {
        float mx = NEG_INF, smv = 0.f;
#pragma unroll
        for (int i = 0; i < 16; ++i) {
            mx = fmaxf(mx, sm.red_mx[i][tid]);
            smv += sm.red_sm[i][tid];
        }
        sm.zacc[tid] += mx;
        sm.zacc[FD + tid] += smv / (float)K;
    }
    // ---- update active set for next level ----
    if (tid < K) sm.anode[tid] = id_;
    if (tid < NPG) sm.nml[tid] = (float)sm.kept[tid];
    __syncthreads();
}

// ---------------------------------------------------------------------------
// Fully-fused kernel: one 1024-thread block per graph does CSR build, all
// 3 GCN+pool levels, readout, and the final MLP + log_softmax.
// ---------------------------------------------------------------------------
__global__ __launch_bounds__(1024)
void k_mega(const float* __restrict__ x, const int* __restrict__ ei,
            const float* __restrict__ W1, const float* __restrict__ b1,
            const float* __restrict__ Wp1, const float* __restrict__ bp1,
            const float* __restrict__ W2, const float* __restrict__ b2,
            const float* __restrict__ Wp2, const float* __restrict__ bp2,
            const float* __restrict__ W3, const float* __restrict__ b3,
            const float* __restrict__ Wp3, const float* __restrict__ bp3,
            const float* __restrict__ Wl1, const float* __restrict__ bl1,
            const float* __restrict__ Wl2, const float* __restrict__ bl2,
            const float* __restrict__ Wl3, const float* __restrict__ bl3,
            float* __restrict__ out) {
    __shared__ SM sm;
    const int g = blockIdx.x, tid = threadIdx.x;
    const int gbase = g * NPG, ebase = g * EPG;
    const int f4 = tid & 31, s = tid >> 5;

    // ---- issue edge + x loads FIRST (latency hides under CSR build) ----
    int myd[4], mys[4];
#pragma unroll
    for (int i = 0; i < 4; ++i) {
        int e = ebase + tid + i * 1024;
        myd[i] = ei[NE + e] - gbase;
        mys[i] = ei[e] - gbase;
    }
    float4 xr[8];
#pragma unroll
    for (int c = 0; c < 8; ++c)
        xr[c] = *(const float4*)&x[((size_t)(gbase + c * NSL + s)) * FD + 4 * f4];

    // ---- CSR-by-dst build: count -> (L1 dinv from degree) -> scan -> scatter
    if (tid < NPG) sm.si[tid] = 0;
    __syncthreads();
#pragma unroll
    for (int i = 0; i < 4; ++i) atomicAdd(&sm.si[myd[i]], 1);
    __syncthreads();
    int vincl = 0, cnt = 0;
    if (tid < NPG) {
        cnt = sm.si[tid];
        sm.dvv[tid] = rsqrtf(1.f + (float)cnt);     // level-1 dinv, for free
        vincl = cnt;
        const int lane = tid & 63;
#pragma unroll
        for (int o = 1; o < 64; o <<= 1) {
            int n = __shfl_up(vincl, o);
            if (lane >= o) vincl += n;
        }
        if (lane == 63) sm.wsum[tid >> 6] = vincl;
    }
    __syncthreads();
    if (tid < NPG) {
        int base = 0;
        for (int w = 0; w < (tid >> 6); ++w) base += sm.wsum[w];
        int excl = base + vincl - cnt;
        sm.rp[tid] = excl;
        sm.kept[tid] = excl;
        if (tid == 0) sm.rp[NPG] = EPG;
        sm.nml[tid] = 1.f;
        sm.anode[tid] = tid;
        sm.zacc[tid] = 0.f;                         // 2*FD == NPG
    }
    __syncthreads();
#pragma unroll
    for (int i = 0; i < 4; ++i) {
        int p = atomicAdd(&sm.kept[myd[i]], 1);
        sm.colb[p] = (unsigned char)mys[i];         // LOCAL src id as byte
    }
    // ---- stage x -> LDS (swizzled) ----
#pragma unroll
    for (int c = 0; c < 8; ++c)
        hsq(sm, c * NSL + s, f4) = xr[c];
    __syncthreads();   // colb + hs + state visible block-wide

    do_level<256, true >(sm, W1, b1, Wp1, bp1, tid);
    do_level<128, false>(sm, W2, b2, Wp2, bp2, tid);
    do_level<64,  false>(sm, W3, b3, Wp3, bp3, tid);

    // ---- final MLP + log_softmax (split-k over sub-threads) ----
    {   // layer 1: 128 outs, 4 subs over k=256
        const int o = tid >> 2, sub = tid & 3;
        if (tid < 512) {
            float a = 0.f;
            for (int k = sub; k < 256; k += 4) a += sm.zacc[k] * Wl1[k * 128 + o];
            a += __shfl_xor(a, 1);
            a += __shfl_xor(a, 2);
            if (sub == 0) sm.sw[o] = fmaxf(a + bl1[o], 0.f);
        }
    }
    __syncthreads();
    {   // layer 2: 64 outs, 4 subs over k=128
        const int o = tid >> 2, sub = tid & 3;
        if (tid < 256) {
            float a = 0.f;
            for (int k = sub; k < 128; k += 4) a += sm.sw[k] * Wl2[k * 64 + o];
            a += __shfl_xor(a, 1);
            a += __shfl_xor(a, 2);
            if (sub == 0) sm.sf[o] = fmaxf(a + bl2[o], 0.f);
        }
    }
    __syncthreads();
    {   // layer 3: 10 outs, 8 subs over k=64
        const int o = tid >> 3, sub = tid & 7;
        if (tid < 8 * NC) {
            float a = 0.f;
            for (int k = sub; k < 64; k += 8) a += sm.sf[k] * Wl3[k * NC + o];
            a += __shfl_xor(a, 1);
            a += __shfl_xor(a, 2);
            a += __shfl_xor(a, 4);
            if (sub == 0) sm.svv[o] = a + bl3[o];
        }
    }
    __syncthreads();
    if (tid == 0) {
        float m = sm.svv[0];
        for (int c = 1; c < NC; ++c) m = fmaxf(m, sm.svv[c]);
        float se = 0.f;
        for (int c = 0; c < NC; ++c) se += expf(sm.svv[c] - m);
        float lse = m + logf(se);
        for (int c = 0; c < NC; ++c) out[g * NC + c] = sm.svv[c] - lse;
    }
}

// ---------------------------------------------------------------------------
extern "C" void kernel_launch(void* const* d_in, const int* in_sizes, int n_in,
                              void* d_out, int out_size, void* d_ws, size_t ws_size,
                              hipStream_t stream) {
    const float* x   = (const float*)d_in[0];
    const int*   ei  = (const int*)d_in[1];
    const float* W1  = (const float*)d_in[3];
    const float* b1  = (const float*)d_in[4];
    const float* Wp1 = (const float*)d_in[5];
    const float* bp1 = (const float*)d_in[6];
    const float* W2  = (const float*)d_in[7];
    const float* b2  = (const float*)d_in[8];
    const float* Wp2 = (const float*)d_in[9];
    const float* bp2 = (const float*)d_in[10];
    const float* W3  = (const float*)d_in[11];
    const float* b3  = (const float*)d_in[12];
    const float* Wp3 = (const float*)d_in[13];
    const float* bp3 = (const float*)d_in[14];
    const float* Wl1 = (const float*)d_in[15];
    const float* bl1 = (const float*)d_in[16];
    const float* Wl2 = (const float*)d_in[17];
    const float* bl2 = (const float*)d_in[18];
    const float* Wl3 = (const float*)d_in[19];
    const float* bl3 = (const float*)d_in[20];
    float* out = (float*)d_out;

    k_mega<<<NB, 1024, 0, stream>>>(x, ei,
                                    W1, b1, Wp1, bp1,
                                    W2, b2, Wp2, bp2,
                                    W3, b3, Wp3, bp3,
                                    Wl1, bl1, Wl2, bl2, Wl3, bl3, out);
}

// Round 9
// 135.111 us; speedup vs baseline: 1.0652x; 1.0652x over previous
//
#include <hip/hip_runtime.h>
#include <math.h>

// Problem constants (fixed by the reference)
#define NB   256                 // graphs
#define NPG  256                 // nodes per graph
#define NN   (NB * NPG)          // 65536 nodes
#define NE   (NN * 16)           // 1048576 edges
#define EPG  (NE / NB)           // 4096 edges per graph
#define FD   128                 // F == H
#define NC   10
#define NSL  32                  // slices (1024 threads / 32 lanes-per-slice)
#define NEG_INF (-3.402823466e38f)

// Shared-memory layout for the fused per-graph block: ~161.9 KB <= 160 KiB.
struct SM {
    float hs[NPG][FD];          // 128 KB: x -> dinv-scaled hW -> gated h (in place)
    int   rp[NPG + 4];          // local CSR row pointers
    float dvv[NPG];             // dinv (next level's computed in prev gate phase)
    float sw[NPG];              // score matvec result / MLP h1
    float sf[NPG];              // score conv result (by node id) / MLP h2
    float svv[NPG];             // sort value staging / MLP logits
    float th[NPG];              // tanh(score) for kept
    float zacc[2 * FD];         // readout accumulator across levels
    int   si[NPG];              // CSR counts / sort index staging
    int   kept[NPG];            // kept flags / CSR scatter cursor
    int   anode[NPG];           // active list
    int   wsum[16];             // wave-scan partials
    float red_mx[16][FD];       // per-wave readout partials
    float red_sm[16][FD];
    unsigned char colb[EPG];    // edge src local ids (CSR-by-dst order), 4 KB
};

// Swizzled access to feature-quad q (16B) of row v: physical quad = q ^ (v&7).
__device__ __forceinline__ float4& hsq(SM& sm, int v, int q) {
    return *(float4*)&sm.hs[v][(q ^ (v & 7)) << 2];
}

// ---------------------------------------------------------------------------
// One pooling level, fully in-LDS. NACT = active node count (256/128/64).
// Thread layout: f4 = tid&31 (feature quad), s = tid>>5 (slice 0..31);
// slice s owns active indices i = c*32+s, c < NPS = NACT/32.
// Precondition: dvv[] holds this level's dinv (degree-based for level 1,
// computed in the previous level's gate phase otherwise); hs rows of active
// nodes hold the gated h input; all other rows are zero.
// ---------------------------------------------------------------------------
template <int NACT, bool LAST>
__device__ __forceinline__ void do_level(SM& sm,
                                         const float* __restrict__ Wmat,
                                         const float* __restrict__ bias,
                                         const float* __restrict__ Wp,
                                         const float* __restrict__ bpp,
                                         int tid) {
    constexpr int NPS = NACT / NSL;      // rows per slice
    constexpr int K   = NACT / 2;
    constexpr int TPN = 1024 / NACT;     // threads per node in score conv
    const int f4 = tid & 31;
    const int s  = tid >> 5;

    // ---- in-place GEMM + dinv prescale: hs[v] <- dvv[v] * (hs[v] @ W) ----
    // Row v is read and written only by the 32 lanes of the half-wave that
    // owns it (lockstep) -> no barrier needed around the in-place update.
    {
        int vr[NPS];
        float4 acc[NPS];
#pragma unroll
        for (int c = 0; c < NPS; ++c) {
            vr[c] = sm.anode[c * NSL + s];
            acc[c] = make_float4(0.f, 0.f, 0.f, 0.f);
        }
#pragma unroll 2
        for (int kq = 0; kq < 32; ++kq) {
            const int k0 = kq << 2;
            float4 w0 = *(const float4*)&Wmat[(k0 + 0) * FD + 4 * f4];
            float4 w1 = *(const float4*)&Wmat[(k0 + 1) * FD + 4 * f4];
            float4 w2 = *(const float4*)&Wmat[(k0 + 2) * FD + 4 * f4];
            float4 w3 = *(const float4*)&Wmat[(k0 + 3) * FD + 4 * f4];
#pragma unroll
            for (int c = 0; c < NPS; ++c) {
                float4 hv = hsq(sm, vr[c], kq);
                acc[c].x += hv.x * w0.x + hv.y * w1.x + hv.z * w2.x + hv.w * w3.x;
                acc[c].y += hv.x * w0.y + hv.y * w1.y + hv.z * w2.y + hv.w * w3.y;
                acc[c].z += hv.x * w0.z + hv.y * w1.z + hv.z * w2.z + hv.w * w3.z;
                acc[c].w += hv.x * w0.w + hv.y * w1.w + hv.z * w2.w + hv.w * w3.w;
            }
        }
#pragma unroll
        for (int c = 0; c < NPS; ++c) {
            const float d = sm.dvv[vr[c]];
            acc[c].x *= d; acc[c].y *= d; acc[c].z *= d; acc[c].w *= d;
            hsq(sm, vr[c], f4) = acc[c];
        }
    }
    __syncthreads();   // publishes scaled GEMM rows

    // ---- conv + relu + fused score matvec (pure-add gather) ----
    const float4 b4  = *(const float4*)&bias[4 * f4];
    const float4 wp4 = *(const float4*)&Wp[4 * f4];
    float4 hreg[NPS];
#pragma unroll
    for (int c = 0; c < NPS; ++c) {
        const int v = sm.anode[c * NSL + s];
        const float dv_ = sm.dvv[v];
        float4 S = hsq(sm, v, f4);                 // scaled self term
        const int e0 = sm.rp[v], e1 = sm.rp[v + 1];
        int e = e0;
        int ea = (e0 + 3) & ~3;                     // align head
        if (ea > e1) ea = e1;
        for (; e < ea; ++e) {
            float4 hu = hsq(sm, sm.colb[e], f4);
            S.x += hu.x; S.y += hu.y; S.z += hu.z; S.w += hu.w;
        }
        for (; e + 4 <= e1; e += 4) {
            unsigned p = *(const unsigned*)&sm.colb[e];
            int u0 = p & 255, u1 = (p >> 8) & 255;
            int u2 = (p >> 16) & 255, u3 = p >> 24;
            float4 h0 = hsq(sm, u0, f4);
            float4 h1 = hsq(sm, u1, f4);
            float4 h2 = hsq(sm, u2, f4);
            float4 h3 = hsq(sm, u3, f4);
            S.x += h0.x + h1.x + h2.x + h3.x;
            S.y += h0.y + h1.y + h2.y + h3.y;
            S.z += h0.z + h1.z + h2.z + h3.z;
            S.w += h0.w + h1.w + h2.w + h3.w;
        }
        for (; e < e1; ++e) {
            float4 hu = hsq(sm, sm.colb[e], f4);
            S.x += hu.x; S.y += hu.y; S.z += hu.z; S.w += hu.w;
        }
        float4 acc;
        acc.x = fmaxf(S.x * dv_ + b4.x, 0.f);
        acc.y = fmaxf(S.y * dv_ + b4.y, 0.f);
        acc.z = fmaxf(S.z * dv_ + b4.z, 0.f);
        acc.w = fmaxf(S.w * dv_ + b4.w, 0.f);
        hreg[c] = acc;
        // score partial: dot(h[v], Wp) reduced across the 32 f4 lanes
        float p = acc.x * wp4.x + acc.y * wp4.y + acc.z * wp4.z + acc.w * wp4.w;
        p += __shfl_xor(p, 1);
        p += __shfl_xor(p, 2);
        p += __shfl_xor(p, 4);
        p += __shfl_xor(p, 8);
        p += __shfl_xor(p, 16);
        if (f4 == 0) sm.sw[v] = p;
    }
    __syncthreads();

    // ---- score conv: TPN threads per active node ----
    {
        const int i = tid / TPN, sub = tid % TPN;
        const int v = sm.anode[i];
        const float dv_ = sm.dvv[v];
        float part = 0.f;
        const int e1 = sm.rp[v + 1];
        for (int e = sm.rp[v] + sub; e < e1; e += TPN) {
            int u = sm.colb[e];
            part += sm.dvv[u] * sm.sw[u];
        }
#pragma unroll
        for (int o = 1; o < TPN; o <<= 1) part += __shfl_xor(part, o);
        if (sub == 0) {
            float acc = sm.sw[v] * dv_ * dv_ + bpp[0] + dv_ * part;
            sm.sf[v] = acc;        // by node id (for tanh later)
            sm.svv[i] = acc;       // by active index (for sort)
        }
    }
    __syncthreads();

    // ---- bitonic sort of NACT active elements, registers + shuffles ----
    // comparator: value desc, node-id asc  (= jax.lax.top_k semantics)
    float v_ = 0.f;
    int   id_ = 0;
    if (tid < NACT) { v_ = sm.svv[tid]; id_ = sm.anode[tid]; }
#pragma unroll
    for (int k = 2; k <= NACT; k <<= 1) {
#pragma unroll
        for (int j = k >> 1; j > 0; j >>= 1) {
            if (j < 64) {
                if (tid < NACT) {
                    float vp = __shfl_xor(v_, j);
                    int  idp = __shfl_xor(id_, j);
                    bool up    = ((tid & k) == 0);
                    bool lower = ((tid & j) == 0);
                    bool g = (v_ > vp) || (v_ == vp && id_ < idp);
                    if (g != (lower == up)) { v_ = vp; id_ = idp; }
                }
            } else {
                if (tid < NACT) { sm.svv[tid] = v_; sm.si[tid] = id_; }
                __syncthreads();
                if (tid < NACT) {
                    int p = tid ^ j;
                    float vp = sm.svv[p];
                    int  idp = sm.si[p];
                    bool up    = ((tid & k) == 0);
                    bool lower = ((tid & j) == 0);
                    bool g = (v_ > vp) || (v_ == vp && id_ < idp);
                    if (g != (lower == up)) { v_ = vp; id_ = idp; }
                }
                __syncthreads();
            }
        }
    }
    if (tid < NPG) sm.kept[tid] = 0;
    __syncthreads();
    if (tid < K) {
        sm.kept[id_] = 1;
        sm.th[id_] = tanhf(sm.sf[id_]);
    }
    __syncthreads();

    // ---- tanh-gate: write kept rows (0 for non-kept); readout partials;
    //      PLUS next level's dinv gather (overlaps with the gate VALU work,
    //      no reader of dvv until the next GEMM epilogue) ----
    float4 mx4 = make_float4(NEG_INF, NEG_INF, NEG_INF, NEG_INF);
    float4 sm4 = make_float4(0.f, 0.f, 0.f, 0.f);
#pragma unroll
    for (int c = 0; c < NPS; ++c) {
        const int v = sm.anode[c * NSL + s];
        const int kp = sm.kept[v];
        const float tg = kp ? sm.th[v] : 0.f;
        float4 val;
        val.x = hreg[c].x * tg;
        val.y = hreg[c].y * tg;
        val.z = hreg[c].z * tg;
        val.w = hreg[c].w * tg;
        hsq(sm, v, f4) = val;                 // zeros dropped rows
        if (kp) {
            mx4.x = fmaxf(mx4.x, val.x);
            mx4.y = fmaxf(mx4.y, val.y);
            mx4.z = fmaxf(mx4.z, val.z);
            mx4.w = fmaxf(mx4.w, val.w);
        }
        sm4.x += val.x; sm4.y += val.y; sm4.z += val.z; sm4.w += val.w;
    }
    mx4.x = fmaxf(mx4.x, __shfl_xor(mx4.x, 32)); sm4.x += __shfl_xor(sm4.x, 32);
    mx4.y = fmaxf(mx4.y, __shfl_xor(mx4.y, 32)); sm4.y += __shfl_xor(sm4.y, 32);
    mx4.z = fmaxf(mx4.z, __shfl_xor(mx4.z, 32)); sm4.z += __shfl_xor(sm4.z, 32);
    mx4.w = fmaxf(mx4.w, __shfl_xor(mx4.w, 32)); sm4.w += __shfl_xor(sm4.w, 32);
    const int wv = tid >> 6;
    if ((tid & 63) < 32) {
        *(float4*)&sm.red_mx[wv][4 * f4] = mx4;
        *(float4*)&sm.red_sm[wv][4 * f4] = sm4;
    }
    if (!LAST) {
        const int n = tid >> 2, sub = tid & 3;
        int cnti = 0;
        const int kpn = sm.kept[n];
        if (kpn) {
            const int e1 = sm.rp[n + 1];
            for (int e = sm.rp[n] + sub; e < e1; e += 4)
                cnti += sm.kept[sm.colb[e]];
        }
        cnti += __shfl_xor(cnti, 1);
        cnti += __shfl_xor(cnti, 2);
        if (sub == 0) sm.dvv[n] = kpn ? rsqrtf(1.f + (float)cnti) : 0.f;
    }
    __syncthreads();
    if (tid < FD) {
        float mx = NEG_INF, smv = 0.f;
#pragma unroll
        for (int i = 0; i < 16; ++i) {
            mx = fmaxf(mx, sm.red_mx[i][tid]);
            smv += sm.red_sm[i][tid];
        }
        sm.zacc[tid] += mx;
        sm.zacc[FD + tid] += smv / (float)K;
    }
    // ---- update active set for next level ----
    if (tid < K) sm.anode[tid] = id_;
    __syncthreads();
}

// ---------------------------------------------------------------------------
// Fully-fused kernel: one 1024-thread block per graph does CSR build, all
// 3 GCN+pool levels, readout, and the final MLP + log_softmax.
// ---------------------------------------------------------------------------
__global__ __launch_bounds__(1024)
void k_mega(const float* __restrict__ x, const int* __restrict__ ei,
            const float* __restrict__ W1, const float* __restrict__ b1,
            const float* __restrict__ Wp1, const float* __restrict__ bp1,
            const float* __restrict__ W2, const float* __restrict__ b2,
            const float* __restrict__ Wp2, const float* __restrict__ bp2,
            const float* __restrict__ W3, const float* __restrict__ b3,
            const float* __restrict__ Wp3, const float* __restrict__ bp3,
            const float* __restrict__ Wl1, const float* __restrict__ bl1,
            const float* __restrict__ Wl2, const float* __restrict__ bl2,
            const float* __restrict__ Wl3, const float* __restrict__ bl3,
            float* __restrict__ out) {
    __shared__ SM sm;
    const int g = blockIdx.x, tid = threadIdx.x;
    const int gbase = g * NPG, ebase = g * EPG;
    const int f4 = tid & 31, s = tid >> 5;

    // ---- read this block's edges once (coalesced) ----
    int myd[4], mys[4];
#pragma unroll
    for (int i = 0; i < 4; ++i) {
        int e = ebase + tid + i * 1024;
        myd[i] = ei[NE + e] - gbase;
        mys[i] = ei[e] - gbase;
    }

    // ---- CSR-by-dst build: count -> (L1 dinv from degree) -> scan -> scatter
    if (tid < NPG) sm.si[tid] = 0;
    __syncthreads();
#pragma unroll
    for (int i = 0; i < 4; ++i) atomicAdd(&sm.si[myd[i]], 1);
    __syncthreads();
    int vincl = 0, cnt = 0;
    if (tid < NPG) {
        cnt = sm.si[tid];
        sm.dvv[tid] = rsqrtf(1.f + (float)cnt);     // level-1 dinv, for free
        vincl = cnt;
        const int lane = tid & 63;
#pragma unroll
        for (int o = 1; o < 64; o <<= 1) {
            int n = __shfl_up(vincl, o);
            if (lane >= o) vincl += n;
        }
        if (lane == 63) sm.wsum[tid >> 6] = vincl;
    }
    __syncthreads();
    if (tid < NPG) {
        int base = 0;
        for (int w = 0; w < (tid >> 6); ++w) base += sm.wsum[w];
        int excl = base + vincl - cnt;
        sm.rp[tid] = excl;
        sm.kept[tid] = excl;
        if (tid == 0) sm.rp[NPG] = EPG;
        sm.anode[tid] = tid;
        sm.zacc[tid] = 0.f;                         // 2*FD == NPG
    }
    __syncthreads();
#pragma unroll
    for (int i = 0; i < 4; ++i) {
        int p = atomicAdd(&sm.kept[myd[i]], 1);
        sm.colb[p] = (unsigned char)mys[i];         // LOCAL src id as byte
    }
    // ---- stage x -> LDS (swizzled) ----
    for (int r = s; r < NPG; r += NSL)
        hsq(sm, r, f4) =
            *(const float4*)&x[((size_t)(gbase + r)) * FD + 4 * f4];
    __syncthreads();   // colb + hs + state visible block-wide

    do_level<256, false>(sm, W1, b1, Wp1, bp1, tid);
    do_level<128, false>(sm, W2, b2, Wp2, bp2, tid);
    do_level<64,  true >(sm, W3, b3, Wp3, bp3, tid);

    // ---- final MLP + log_softmax (split-k over sub-threads) ----
    {   // layer 1: 128 outs, 4 subs over k=256
        const int o = tid >> 2, sub = tid & 3;
        if (tid < 512) {
            float a = 0.f;
            for (int k = sub; k < 256; k += 4) a += sm.zacc[k] * Wl1[k * 128 + o];
            a += __shfl_xor(a, 1);
            a += __shfl_xor(a, 2);
            if (sub == 0) sm.sw[o] = fmaxf(a + bl1[o], 0.f);
        }
    }
    __syncthreads();
    {   // layer 2: 64 outs, 4 subs over k=128
        const int o = tid >> 2, sub = tid & 3;
        if (tid < 256) {
            float a = 0.f;
            for (int k = sub; k < 128; k += 4) a += sm.sw[k] * Wl2[k * 64 + o];
            a += __shfl_xor(a, 1);
            a += __shfl_xor(a, 2);
            if (sub == 0) sm.sf[o] = fmaxf(a + bl2[o], 0.f);
        }
    }
    __syncthreads();
    {   // layer 3: 10 outs, 8 subs over k=64
        const int o = tid >> 3, sub = tid & 7;
        if (tid < 8 * NC) {
            float a = 0.f;
            for (int k = sub; k < 64; k += 8) a += sm.sf[k] * Wl3[k * NC + o];
            a += __shfl_xor(a, 1);
            a += __shfl_xor(a, 2);
            a += __shfl_xor(a, 4);
            if (sub == 0) sm.svv[o] = a + bl3[o];
        }
    }
    __syncthreads();
    if (tid == 0) {
        float m = sm.svv[0];
        for (int c = 1; c < NC; ++c) m = fmaxf(m, sm.svv[c]);
        float se = 0.f;
        for (int c = 0; c < NC; ++c) se += expf(sm.svv[c] - m);
        float lse = m + logf(se);
        for (int c = 0; c < NC; ++c) out[g * NC + c] = sm.svv[c] - lse;
    }
}

// ---------------------------------------------------------------------------
extern "C" void kernel_launch(void* const* d_in, const int* in_sizes, int n_in,
                              void* d_out, int out_size, void* d_ws, size_t ws_size,
                              hipStream_t stream) {
    const float* x   = (const float*)d_in[0];
    const int*   ei  = (const int*)d_in[1];
    const float* W1  = (const float*)d_in[3];
    const float* b1  = (const float*)d_in[4];
    const float* Wp1 = (const float*)d_in[5];
    const float* bp1 = (const float*)d_in[6];
    const float* W2  = (const float*)d_in[7];
    const float* b2  = (const float*)d_in[8];
    const float* Wp2 = (const float*)d_in[9];
    const float* bp2 = (const float*)d_in[10];
    const float* W3  = (const float*)d_in[11];
    const float* b3  = (const float*)d_in[12];
    const float* Wp3 = (const float*)d_in[13];
    const float* bp3 = (const float*)d_in[14];
    const float* Wl1 = (const float*)d_in[15];
    const float* bl1 = (const float*)d_in[16];
    const float* Wl2 = (const float*)d_in[17];
    const float* bl2 = (const float*)d_in[18];
    const float* Wl3 = (const float*)d_in[19];
    const float* bl3 = (const float*)d_in[20];
    float* out = (float*)d_out;

    k_mega<<<NB, 1024, 0, stream>>>(x, ei,
                                    W1, b1, Wp1, bp1,
                                    W2, b2, Wp2, bp2,
                                    W3, b3, Wp3, bp3,
                                    Wl1, bl1, Wl2, bl2, Wl3, bl3, out);
}